// Round 6
// baseline (111.479 us; speedup 1.0000x reference)
//
#include <hip/hip_runtime.h>
#include <hip/hip_bf16.h>
#include <math.h>

#define BB 4
#define SS 4096
#define DD 64
#define KSPLIT 4      // pb k-splits
#define QSPLIT 8      // pa q-splits

typedef __attribute__((ext_vector_type(8))) short short8;
typedef __attribute__((ext_vector_type(4))) float f32x4;
typedef __attribute__((ext_vector_type(2))) unsigned int u32x2;
typedef unsigned int u32;
typedef unsigned short ushort_t;

#define MFMA16(a,b,c) __builtin_amdgcn_mfma_f32_16x16x32_bf16((a),(b),(c),0,0,0)
// exp(s/64) == exp2(s * C2SC)
#define C2SC 0.022542110700140054f

union Pk8 { short8 s8; u32 u[4]; u32x2 h[2]; };

static __device__ __forceinline__ unsigned short f2bf(float f) {
  union { float f; u32 u; } x; x.f = f;
  u32 r = (x.u + 0x7FFFu + ((x.u >> 16) & 1u)) >> 16;
  return (unsigned short)r;
}

// compiler lowers this to v_cvt_pk_bf16_f32 (do NOT hand-twiddle: VALU-bound)
static __device__ __forceinline__ u32 pk2(float a, float b) {
  __hip_bfloat16 lo = __float2bfloat16(a);
  __hip_bfloat16 hi = __float2bfloat16(b);
  unsigned short ls, hs;
  __builtin_memcpy(&ls, &lo, 2); __builtin_memcpy(&hs, &hi, 2);
  return (u32)ls | ((u32)hs << 16);
}

// ---------------- P0: convert Q,K -> bf16; zero out0 and z2
__global__ __launch_bounds__(256) void p0_convert(
    const float* __restrict__ q, const float* __restrict__ k,
    ushort_t* __restrict__ QB, ushort_t* __restrict__ KB,
    float* __restrict__ out0, float* __restrict__ z2)
{
  const size_t i = (size_t)blockIdx.x * 256 + threadIdx.x;  // over BB*SS*DD/4
  float4 a = ((const float4*)q)[i];
  float4 c = ((const float4*)k)[i];
  ((ushort4*)QB)[i] = make_ushort4(f2bf(a.x), f2bf(a.y), f2bf(a.z), f2bf(a.w));
  ((ushort4*)KB)[i] = make_ushort4(f2bf(c.x), f2bf(c.y), f2bf(c.z), f2bf(c.w));
  ((float4*)out0)[i] = make_float4(0.f, 0.f, 0.f, 0.f);
  if (blockIdx.x == 0) z2[threadIdx.x] = 0.f;
}

// ============ PA: Z[k] partial = sum_{q in chunk} exp(s_qk), all-register ============
// grid (SS/128, QSPLIT, BB), 256 thr. Wave w owns k rows 32w..32w+31 (K in regs).
static __device__ __forceinline__ void load_q4(
    short8 bq[4][2], const ushort_t* __restrict__ QB, size_t qrow, int g)
{
#pragma unroll
  for (int qt = 0; qt < 4; ++qt)
#pragma unroll
    for (int dh = 0; dh < 2; ++dh)
      bq[qt][dh] = *(const short8*)(QB + (qrow + 16*qt)*DD + 32*dh + 8*g);
}

static __device__ __forceinline__ void pa_tile(
    const short8 ak[2][2], const short8 bq[4][2], float z[8])
{
#pragma unroll
  for (int qt = 0; qt < 4; ++qt)
#pragma unroll
    for (int s = 0; s < 2; ++s) {
      f32x4 a = {0.f,0.f,0.f,0.f};
      a = MFMA16(ak[s][0], bq[qt][0], a);
      a = MFMA16(ak[s][1], bq[qt][1], a);
      z[4*s+0] += exp2f(a[0]*C2SC); z[4*s+1] += exp2f(a[1]*C2SC);
      z[4*s+2] += exp2f(a[2]*C2SC); z[4*s+3] += exp2f(a[3]*C2SC);
    }
}

__global__ __launch_bounds__(256, 4) void pa_colsum(
    const ushort_t* __restrict__ QB, const ushort_t* __restrict__ KB,
    float* __restrict__ Zp)
{
  const int kb0 = blockIdx.x * 128;
  const int qch = blockIdx.y;
  const int b   = blockIdx.z;
  const int t = threadIdx.x, w = t >> 6, lane = t & 63;
  const int g = lane >> 4, r15 = lane & 15;
  const int QCH = SS / QSPLIT;         // 512

  // K fragments in registers: 2 subtiles of 16 k-rows each
  short8 ak[2][2];
#pragma unroll
  for (int s = 0; s < 2; ++s)
#pragma unroll
    for (int dh = 0; dh < 2; ++dh)
      ak[s][dh] = *(const short8*)(KB + ((size_t)b*SS + kb0 + 32*w + 16*s + r15)*DD + 32*dh + 8*g);

  float z[8];
#pragma unroll
  for (int i = 0; i < 8; ++i) z[i] = 0.f;

  const size_t qrow0 = (size_t)b*SS + qch*QCH + r15;
  short8 bqA[4][2], bqB[4][2];
  load_q4(bqA, QB, qrow0, g);

#pragma unroll 1
  for (int tt = 0; tt < QCH/64; tt += 2) {
    load_q4(bqB, QB, qrow0 + (size_t)(tt+1)*64, g);
    pa_tile(ak, bqA, z);
    if (tt + 2 < QCH/64) load_q4(bqA, QB, qrow0 + (size_t)(tt+2)*64, g);
    pa_tile(ak, bqB, z);
  }

#pragma unroll
  for (int m = 1; m < 16; m <<= 1)
#pragma unroll
    for (int i = 0; i < 8; ++i) z[i] += __shfl_xor(z[i], m);
  if (r15 == 0) {
#pragma unroll
    for (int s = 0; s < 2; ++s)
#pragma unroll
      for (int r = 0; r < 4; ++r)
        Zp[((size_t)qch*BB + b)*SS + kb0 + 32*w + 16*s + 4*g + r] = z[4*s+r];
  }
}

// ---------------- P2: VT[b][d][s] = bf16( V[b][s][d] / Z[s] )
__global__ __launch_bounds__(256) void p2_vt(
    const float* __restrict__ v, const float* __restrict__ Zp,
    ushort_t* __restrict__ VT)
{
  const int k0 = blockIdx.x * 64;
  const int b  = blockIdx.y;
  const int t = threadIdx.x;
  __shared__ float vs[64][65];
  __shared__ float izs[64];
  {
    const int row = t >> 2, cq = (t & 3) * 16;
    const float* src = v + ((size_t)b*SS + k0 + row)*DD + cq;
#pragma unroll
    for (int i = 0; i < 4; ++i) {
      float4 x = ((const float4*)src)[i];
      vs[row][cq + 4*i + 0] = x.x; vs[row][cq + 4*i + 1] = x.y;
      vs[row][cq + 4*i + 2] = x.z; vs[row][cq + 4*i + 3] = x.w;
    }
  }
  if (t < 64) {
    float z = 0.f;
#pragma unroll
    for (int c = 0; c < QSPLIT; ++c)
      z += Zp[((size_t)c*BB + b)*SS + k0 + t];
    izs[t] = 1.0f / z;
  }
  __syncthreads();
  const int d = t >> 2, ks = (t & 3) * 16;
  u32* dst = (u32*)VT + (((size_t)b*DD + d)*SS + k0 + ks)/2;
#pragma unroll
  for (int i = 0; i < 8; ++i) {
    float a0 = vs[ks + 2*i    ][d] * izs[ks + 2*i    ];
    float a1 = vs[ks + 2*i + 1][d] * izs[ks + 2*i + 1];
    dst[i] = (u32)f2bf(a0) | ((u32)f2bf(a1) << 16);
  }
}

// ============ PB: attn += exp(QK^T/64) * VT, all-register main loop ============
// grid (SS/64, KSPLIT, BB), 256 thr. Wave w owns k-slice 16w/16w+64 of each 128-k
// step; Q (64 rows) + K-slice + V-frags in registers; P never leaves registers.
static __device__ __forceinline__ void load_k2(
    short8 ka[2][2], const ushort_t* __restrict__ KB, size_t krow, int g)
{
#pragma unroll
  for (int s = 0; s < 2; ++s)
#pragma unroll
    for (int dh = 0; dh < 2; ++dh)
      ka[s][dh] = *(const short8*)(KB + (krow + 64*s)*DD + 32*dh + 8*g);
}

static __device__ __forceinline__ void load_v4(
    short8 bv[4], const ushort_t* __restrict__ VT, size_t voff)
{
#pragma unroll
  for (int dt = 0; dt < 4; ++dt) {
    Pk8 u;
    u.h[0] = *(const u32x2*)(VT + voff + (size_t)16*dt*SS);
    u.h[1] = *(const u32x2*)(VT + voff + (size_t)16*dt*SS + 64);
    bv[dt] = u.s8;
  }
}

static __device__ __forceinline__ void pb_tile(
    const short8 ka[2][2], const short8 bv[4], const short8 aq[4][2],
    f32x4 acc[4][4])
{
  u32 pk[2][4][2];
#pragma unroll
  for (int s = 0; s < 2; ++s)
#pragma unroll
    for (int qt = 0; qt < 4; ++qt) {
      f32x4 a = {0.f,0.f,0.f,0.f};
      a = MFMA16(ka[s][0], aq[qt][0], a);
      a = MFMA16(ka[s][1], aq[qt][1], a);
      pk[s][qt][0] = pk2(exp2f(a[0]*C2SC), exp2f(a[1]*C2SC));
      pk[s][qt][1] = pk2(exp2f(a[2]*C2SC), exp2f(a[3]*C2SC));
    }
#pragma unroll
  for (int qt = 0; qt < 4; ++qt) {
    Pk8 ap;
    ap.u[0] = pk[0][qt][0]; ap.u[1] = pk[0][qt][1];
    ap.u[2] = pk[1][qt][0]; ap.u[3] = pk[1][qt][1];
#pragma unroll
    for (int dt = 0; dt < 4; ++dt)
      acc[qt][dt] = MFMA16(ap.s8, bv[dt], acc[qt][dt]);
  }
}

__global__ __launch_bounds__(256, 2) void pb_attn(
    const ushort_t* __restrict__ QB, const ushort_t* __restrict__ KB,
    const ushort_t* __restrict__ VT, float* __restrict__ out0)
{
  const int q0 = blockIdx.x * 64;
  const int kbase = blockIdx.y * (SS / KSPLIT);
  const int b  = blockIdx.z;
  const int t = threadIdx.x, w = t >> 6, lane = t & 63;
  const int g = lane >> 4, r15 = lane & 15;
  const int NT = SS / KSPLIT / 128;    // 8

  __shared__ f32x4 red[3][16][64];     // 48 KB, epilogue only

  // Q fragments in registers: all 64 q rows
  short8 aq[4][2];
#pragma unroll
  for (int qt = 0; qt < 4; ++qt)
#pragma unroll
    for (int dh = 0; dh < 2; ++dh)
      aq[qt][dh] = *(const short8*)(QB + ((size_t)b*SS + q0 + 16*qt + r15)*DD + 32*dh + 8*g);

  f32x4 acc[4][4];
#pragma unroll
  for (int qt = 0; qt < 4; ++qt)
#pragma unroll
    for (int dt = 0; dt < 4; ++dt) acc[qt][dt] = (f32x4){0.f,0.f,0.f,0.f};

  const size_t krow0 = (size_t)b*SS + kbase + 16*w + r15;       // + kt*128 (+64s)
  const size_t voff0 = ((size_t)b*DD + r15)*SS + kbase + 16*w + 4*g;  // + kt*128

  short8 kaA[2][2], kaB[2][2], bvA[4], bvB[4];
  load_k2(kaA, KB, krow0, g);
  load_v4(bvA, VT, voff0);

#pragma unroll 1
  for (int kt = 0; kt < NT; kt += 2) {
    load_k2(kaB, KB, krow0 + (size_t)(kt+1)*128, g);
    load_v4(bvB, VT, voff0 + (size_t)(kt+1)*128);
    pb_tile(kaA, bvA, aq, acc);
    if (kt + 2 < NT) {
      load_k2(kaA, KB, krow0 + (size_t)(kt+2)*128, g);
      load_v4(bvA, VT, voff0 + (size_t)(kt+2)*128);
    }
    pb_tile(kaB, bvB, aq, acc);
  }

  // cross-wave reduction through 48KB LDS, then wave 0 atomics
  if (w > 0) {
#pragma unroll
    for (int qt = 0; qt < 4; ++qt)
#pragma unroll
      for (int dt = 0; dt < 4; ++dt) red[w-1][qt*4+dt][lane] = acc[qt][dt];
  }
  __syncthreads();
  if (w == 0) {
#pragma unroll
    for (int qt = 0; qt < 4; ++qt)
#pragma unroll
      for (int dt = 0; dt < 4; ++dt) {
        f32x4 s = acc[qt][dt] + red[0][qt*4+dt][lane]
                + red[1][qt*4+dt][lane] + red[2][qt*4+dt][lane];
#pragma unroll
        for (int rr = 0; rr < 4; ++rr)
          atomicAdd(&out0[((size_t)b*SS + q0 + 16*qt + 4*g + rr)*DD + 16*dt + r15], s[rr]);
      }
  }
}

// ---------------- K4F: column sum of exp(attn) over q -> z2 (atomic)
// grid (BB, SS/32), 256 thr.
__global__ __launch_bounds__(256) void k4f(
    const float* __restrict__ attn, float* __restrict__ z2)
{
  const int b = blockIdx.x;
  const int q0 = blockIdx.y * 32;
  const int t = threadIdx.x;
  const int d = t & 63, rg = t >> 6;
  float ze = 0.f;
#pragma unroll
  for (int i = 0; i < 8; ++i) {
    float a = attn[((size_t)b*SS + q0 + 4*i + rg)*DD + d];
    ze += __expf(a);
  }
  __shared__ float red[4][64];
  red[rg][d] = ze;
  __syncthreads();
  if (t < 64)
    atomicAdd(&z2[b*DD + t], red[0][t] + red[1][t] + red[2][t] + red[3][t]);
}

// ---------------- K6: attn_w = exp(attn) / z2
__global__ __launch_bounds__(256) void k6w(
    const float* __restrict__ attn, const float* __restrict__ z2,
    float* __restrict__ out1)
{
  const size_t i = (size_t)blockIdx.x * 256 + threadIdx.x;
  const int b = (int)(i >> 18);        // SS*DD = 262144
  const int d = (int)(i & 63);
  out1[i] = __expf(attn[i]) / z2[b*DD + d];
}

extern "C" void kernel_launch(void* const* d_in, const int* in_sizes, int n_in,
                              void* d_out, int out_size, void* d_ws, size_t ws_size,
                              hipStream_t stream) {
  const float* q = (const float*)d_in[0];
  const float* k = (const float*)d_in[1];
  const float* v = (const float*)d_in[2];
  float* out0 = (float*)d_out;
  float* out1 = out0 + (size_t)BB * SS * DD;

  // bf16 Q/K scratch lives in the out1 region (overwritten by k6w at the end).
  ushort_t* QB = (ushort_t*)out1;                 // 2 MB
  ushort_t* KB = QB + (size_t)BB * SS * DD;       // 2 MB

  float* ws = (float*)d_ws;
  ushort_t* VT = (ushort_t*)ws;                              // 2 MB bf16
  float* Zp = (float*)(VT + (size_t)BB * DD * SS);           // QSPLIT*BB*SS
  float* z2 = Zp + (size_t)QSPLIT * BB * SS;                 // BB*DD

  hipLaunchKernelGGL(p0_convert, dim3(BB*SS*DD/4/256), dim3(256), 0, stream, q, k, QB, KB, out0, z2);
  hipLaunchKernelGGL(pa_colsum, dim3(SS/128, QSPLIT, BB), dim3(256), 0, stream, QB, KB, Zp);
  hipLaunchKernelGGL(p2_vt, dim3(SS/64, BB), dim3(256), 0, stream, v, Zp, VT);
  hipLaunchKernelGGL(pb_attn, dim3(SS/64, KSPLIT, BB), dim3(256), 0, stream, QB, KB, VT, out0);
  hipLaunchKernelGGL(k4f, dim3(BB, SS/32), dim3(256), 0, stream, out0, z2);
  hipLaunchKernelGGL(k6w, dim3(BB*SS*DD/256), dim3(256), 0, stream, out0, z2, out1);
}

// Round 7
// 85.959 us; speedup vs baseline: 1.2969x; 1.2969x over previous
//
#include <hip/hip_runtime.h>
#include <hip/hip_bf16.h>
#include <math.h>

#define BB 4
#define SS 4096
#define DD 64
#define KSPLIT 4      // pb k-splits
#define QSPLIT 8      // pa q-splits

typedef __attribute__((ext_vector_type(8))) short short8;
typedef __attribute__((ext_vector_type(4))) float f32x4;
typedef __attribute__((ext_vector_type(2))) unsigned int u32x2;
typedef unsigned int u32;
typedef unsigned short ushort_t;

#define MFMA16(a,b,c) __builtin_amdgcn_mfma_f32_16x16x32_bf16((a),(b),(c),0,0,0)
// exp(s/64) == exp2(s * C2SC)
#define C2SC 0.022542110700140054f

// Raw barrier: do NOT use __syncthreads() in pipelined loops — it emits
// s_waitcnt vmcnt(0) lgkmcnt(0) and drains the prefetch queue.
#define BAR() do { asm volatile("" ::: "memory"); \
                   __builtin_amdgcn_s_barrier();  \
                   asm volatile("" ::: "memory"); } while (0)
#define WAIT_VM(N)  asm volatile("s_waitcnt vmcnt(" #N ")" ::: "memory")
#define WAIT_LGKM() asm volatile("s_waitcnt lgkmcnt(0)" ::: "memory")

union Pk8 { short8 s8; u32 u[4]; u32x2 h[2]; };

static __device__ __forceinline__ unsigned short f2bf(float f) {
  union { float f; u32 u; } x; x.f = f;
  u32 r = (x.u + 0x7FFFu + ((x.u >> 16) & 1u)) >> 16;
  return (unsigned short)r;
}

// compiler lowers to v_cvt_pk_bf16_f32
static __device__ __forceinline__ u32 pk2(float a, float b) {
  __hip_bfloat16 lo = __float2bfloat16(a);
  __hip_bfloat16 hi = __float2bfloat16(b);
  unsigned short ls, hs;
  __builtin_memcpy(&ls, &lo, 2); __builtin_memcpy(&hs, &hi, 2);
  return (u32)ls | ((u32)hs << 16);
}

static __device__ __forceinline__ void gload16(const void* g, void* l) {
  __builtin_amdgcn_global_load_lds((const __attribute__((address_space(1))) u32*)g,
                                   (__attribute__((address_space(3))) u32*)l, 16, 0, 0);
}

// ---------------- P0: convert Q,K -> bf16; zero out0 and z2
__global__ __launch_bounds__(256) void p0_convert(
    const float* __restrict__ q, const float* __restrict__ k,
    ushort_t* __restrict__ QB, ushort_t* __restrict__ KB,
    float* __restrict__ out0, float* __restrict__ z2)
{
  const size_t i = (size_t)blockIdx.x * 256 + threadIdx.x;  // over BB*SS*DD/4
  float4 a = ((const float4*)q)[i];
  float4 c = ((const float4*)k)[i];
  ((ushort4*)QB)[i] = make_ushort4(f2bf(a.x), f2bf(a.y), f2bf(a.z), f2bf(a.w));
  ((ushort4*)KB)[i] = make_ushort4(f2bf(c.x), f2bf(c.y), f2bf(c.z), f2bf(c.w));
  ((float4*)out0)[i] = make_float4(0.f, 0.f, 0.f, 0.f);
  if (blockIdx.x == 0) z2[threadIdx.x] = 0.f;
}

// ============ PA: Z[k] partial = sum_{q in chunk} exp(s_qk) ============
// grid (SS/128, QSPLIT, BB), 256 thr. Wave w owns k rows 32w..32w+31 (K in regs);
// Q tiles staged via gload_lds, double-buffered, counted vmcnt.
__global__ __launch_bounds__(256, 4) void pa_colsum(
    const ushort_t* __restrict__ QB, const ushort_t* __restrict__ KB,
    float* __restrict__ Zp)
{
  const int kb0 = blockIdx.x * 128;
  const int qch = blockIdx.y;
  const int b   = blockIdx.z;
  const int t = threadIdx.x, w = t >> 6, lane = t & 63;
  const int g = lane >> 4, r15 = lane & 15;
  const int QCH = SS / QSPLIT;         // 512
  const int NT = QCH / 64;             // 8

  __shared__ alignas(16) char qbuf[2][64*128];   // 16 KB

  // K fragments in registers: 2 subtiles of 16 k-rows each
  short8 ak[2][2];
#pragma unroll
  for (int s = 0; s < 2; ++s)
#pragma unroll
    for (int dh = 0; dh < 2; ++dh)
      ak[s][dh] = *(const short8*)(KB + ((size_t)b*SS + kb0 + 32*w + 16*s + r15)*DD + 32*dh + 8*g);

  const int q0g = qch * QCH;
  // stage(tile): 64 rows x 128B, swizzled source, linear dest
#define PA_STAGE(tt, buf) do {                                              \
    _Pragma("unroll")                                                       \
    for (int j = 0; j < 2; ++j) {                                           \
      const int row = 16*w + 8*j + (lane >> 3);                             \
      const char* gsrc = (const char*)(QB + ((size_t)b*SS + q0g + (tt)*64 + row)*DD) \
                         + 16*((lane & 7) ^ (row & 7));                     \
      gload16(gsrc, qbuf[buf] + (16*w + 8*j)*128);                          \
    }                                                                       \
  } while (0)

  PA_STAGE(0, 0);

  float z[8];
#pragma unroll
  for (int i = 0; i < 8; ++i) z[i] = 0.f;

#pragma unroll 1
  for (int tt = 0; tt < NT; ++tt) {
    if (tt < NT-1) {
      PA_STAGE(tt+1, (tt+1)&1);
      WAIT_VM(2);
    } else {
      WAIT_VM(0);
    }
    BAR();
    const char* qb = qbuf[tt & 1];
#pragma unroll
    for (int qt = 0; qt < 4; ++qt) {
      const int qrow = 16*qt + r15;
      const char* base = qb + qrow*128;
      short8 bq0 = *(const short8*)(base + 16*((g    ) ^ (qrow & 7)));
      short8 bq1 = *(const short8*)(base + 16*((4 + g) ^ (qrow & 7)));
#pragma unroll
      for (int s = 0; s < 2; ++s) {
        f32x4 a = {0.f,0.f,0.f,0.f};
        a = MFMA16(ak[s][0], bq0, a);
        a = MFMA16(ak[s][1], bq1, a);
        z[4*s+0] += exp2f(a[0]*C2SC); z[4*s+1] += exp2f(a[1]*C2SC);
        z[4*s+2] += exp2f(a[2]*C2SC); z[4*s+3] += exp2f(a[3]*C2SC);
      }
    }
    WAIT_LGKM();
    BAR();
  }
#undef PA_STAGE

#pragma unroll
  for (int m = 1; m < 16; m <<= 1)
#pragma unroll
    for (int i = 0; i < 8; ++i) z[i] += __shfl_xor(z[i], m);
  if (r15 == 0) {
#pragma unroll
    for (int s = 0; s < 2; ++s)
#pragma unroll
      for (int r = 0; r < 4; ++r)
        Zp[((size_t)qch*BB + b)*SS + kb0 + 32*w + 16*s + 4*g + r] = z[4*s+r];
  }
}

// ---------------- P2: VT[b][d][s] = bf16( V[b][s][d] / Z[s] )
__global__ __launch_bounds__(256) void p2_vt(
    const float* __restrict__ v, const float* __restrict__ Zp,
    ushort_t* __restrict__ VT)
{
  const int k0 = blockIdx.x * 64;
  const int b  = blockIdx.y;
  const int t = threadIdx.x;
  __shared__ float vs[64][65];
  __shared__ float izs[64];
  {
    const int row = t >> 2, cq = (t & 3) * 16;
    const float* src = v + ((size_t)b*SS + k0 + row)*DD + cq;
#pragma unroll
    for (int i = 0; i < 4; ++i) {
      float4 x = ((const float4*)src)[i];
      vs[row][cq + 4*i + 0] = x.x; vs[row][cq + 4*i + 1] = x.y;
      vs[row][cq + 4*i + 2] = x.z; vs[row][cq + 4*i + 3] = x.w;
    }
  }
  if (t < 64) {
    float z = 0.f;
#pragma unroll
    for (int c = 0; c < QSPLIT; ++c)
      z += Zp[((size_t)c*BB + b)*SS + k0 + t];
    izs[t] = 1.0f / z;
  }
  __syncthreads();
  const int d = t >> 2, ks = (t & 3) * 16;
  u32* dst = (u32*)VT + (((size_t)b*DD + d)*SS + k0 + ks)/2;
#pragma unroll
  for (int i = 0; i < 8; ++i) {
    float a0 = vs[ks + 2*i    ][d] * izs[ks + 2*i    ];
    float a1 = vs[ks + 2*i + 1][d] * izs[ks + 2*i + 1];
    dst[i] = (u32)f2bf(a0) | ((u32)f2bf(a1) << 16);
  }
}

// ============ PB: attn += exp(QK^T/64) * VT ============
// grid (SS/64, KSPLIT, BB), 256 thr. Wave w owns k-slices 16w and 64+16w of each
// 128-k step; Q (64 rows) in regs; P never leaves registers (pi-paired PV);
// K/V staged via gload_lds, double-buffered, counted vmcnt across raw barriers.
__global__ __launch_bounds__(256, 2) void pb_attn(
    const ushort_t* __restrict__ QB, const ushort_t* __restrict__ KB,
    const ushort_t* __restrict__ VT, float* __restrict__ out0)
{
  const int q0 = blockIdx.x * 64;
  const int kbase = blockIdx.y * (SS / KSPLIT);
  const int b  = blockIdx.z;
  const int t = threadIdx.x, w = t >> 6, lane = t & 63;
  const int g = lane >> 4, r15 = lane & 15;
  const int NT = SS / KSPLIT / 128;    // 8

  __shared__ alignas(16) char smem[65536];   // [2][16KB K] + [2][16KB V]; epilogue reuse
  char* kbuf = smem;            // kbuf[buf] = smem + buf*16384
  char* vbuf = smem + 32768;    // vbuf[buf] = smem+32768 + buf*16384

  // Q fragments in registers: all 64 q rows
  short8 aq[4][2];
#pragma unroll
  for (int qt = 0; qt < 4; ++qt)
#pragma unroll
    for (int dh = 0; dh < 2; ++dh)
      aq[qt][dh] = *(const short8*)(QB + ((size_t)b*SS + q0 + 16*qt + r15)*DD + 32*dh + 8*g);

  f32x4 acc[4][4];
#pragma unroll
  for (int qt = 0; qt < 4; ++qt)
#pragma unroll
    for (int dt = 0; dt < 4; ++dt) acc[qt][dt] = (f32x4){0.f,0.f,0.f,0.f};

  // stage(tile kt into buf): K 128x128B + V 64x256B, swizzled source, linear dest
#define PB_STAGE(kt, buf) do {                                               \
    const int kc = kbase + (kt)*128;                                         \
    _Pragma("unroll")                                                        \
    for (int j = 0; j < 4; ++j) {                                            \
      const int row = 32*j + 8*w + (lane >> 3);                              \
      const char* gk = (const char*)(KB + ((size_t)b*SS + kc + row)*DD)      \
                       + 16*((lane & 7) ^ (row & 7));                        \
      gload16(gk, kbuf + (buf)*16384 + (32*j + 8*w)*128);                    \
    }                                                                        \
    _Pragma("unroll")                                                        \
    for (int j = 0; j < 4; ++j) {                                            \
      const int row = 16*j + 4*w + (lane >> 4);                              \
      const char* gv = (const char*)(VT + ((size_t)b*DD + row)*SS + kc)      \
                       + 16*((lane & 15) ^ (row & 15));                      \
      gload16(gv, vbuf + (buf)*16384 + (16*j + 4*w)*256);                    \
    }                                                                        \
  } while (0)

  PB_STAGE(0, 0);

#pragma unroll 1
  for (int kt = 0; kt < NT; ++kt) {
    if (kt < NT-1) {
      PB_STAGE(kt+1, (kt+1)&1);
      WAIT_VM(8);
    } else {
      WAIT_VM(0);
    }
    BAR();
    const char* kb = kbuf + (kt&1)*16384;
    const char* vb = vbuf + (kt&1)*16384;

    // QK^T (swapped: A=K, B=Q); P packed into registers
    u32 pk[2][4][2];
#pragma unroll
    for (int s = 0; s < 2; ++s) {
      const int rowA = 64*s + 16*w + r15;
      const char* base = kb + rowA*128;
      short8 ka0 = *(const short8*)(base + 16*((g    ) ^ (rowA & 7)));
      short8 ka1 = *(const short8*)(base + 16*((4 + g) ^ (rowA & 7)));
#pragma unroll
      for (int qt = 0; qt < 4; ++qt) {
        f32x4 a = {0.f,0.f,0.f,0.f};
        a = MFMA16(ka0, aq[qt][0], a);
        a = MFMA16(ka1, aq[qt][1], a);
        pk[s][qt][0] = pk2(exp2f(a[0]*C2SC), exp2f(a[1]*C2SC));
        pk[s][qt][1] = pk2(exp2f(a[2]*C2SC), exp2f(a[3]*C2SC));
      }
    }
    // V fragments (pi-paired k ordering), gathered from LDS
    short8 bv[4];
#pragma unroll
    for (int dt = 0; dt < 4; ++dt) {
      const int vrow = 16*dt + r15;
      Pk8 u;
      u.h[0] = *(const u32x2*)(vb + vrow*256 + 16*((    2*w + (g>>1)) ^ r15) + 8*(g&1));
      u.h[1] = *(const u32x2*)(vb + vrow*256 + 16*((8 + 2*w + (g>>1)) ^ r15) + 8*(g&1));
      bv[dt] = u.s8;
    }
    // PV: A = P (registers), kdim pairs subtiles {s=0, s=1}
#pragma unroll
    for (int qt = 0; qt < 4; ++qt) {
      Pk8 ap;
      ap.u[0] = pk[0][qt][0]; ap.u[1] = pk[0][qt][1];
      ap.u[2] = pk[1][qt][0]; ap.u[3] = pk[1][qt][1];
#pragma unroll
      for (int dt = 0; dt < 4; ++dt)
        acc[qt][dt] = MFMA16(ap.s8, bv[dt], acc[qt][dt]);
    }
    WAIT_LGKM();
    BAR();
  }
#undef PB_STAGE

  // cross-wave reduction through reused LDS (48KB), then wave 0 atomics
  f32x4* red = (f32x4*)smem;   // [3][16][64]
  if (w > 0) {
#pragma unroll
    for (int qt = 0; qt < 4; ++qt)
#pragma unroll
      for (int dt = 0; dt < 4; ++dt) red[((w-1)*16 + qt*4+dt)*64 + lane] = acc[qt][dt];
  }
  __syncthreads();
  if (w == 0) {
#pragma unroll
    for (int qt = 0; qt < 4; ++qt)
#pragma unroll
      for (int dt = 0; dt < 4; ++dt) {
        f32x4 s = acc[qt][dt] + red[(0*16 + qt*4+dt)*64 + lane]
                + red[(1*16 + qt*4+dt)*64 + lane] + red[(2*16 + qt*4+dt)*64 + lane];
#pragma unroll
        for (int rr = 0; rr < 4; ++rr)
          atomicAdd(&out0[((size_t)b*SS + q0 + 16*qt + 4*g + rr)*DD + 16*dt + r15], s[rr]);
      }
  }
}

// ---------------- K4F: column sum of exp(attn) over q -> z2 (atomic)
// grid (BB, SS/32), 256 thr.
__global__ __launch_bounds__(256) void k4f(
    const float* __restrict__ attn, float* __restrict__ z2)
{
  const int b = blockIdx.x;
  const int q0 = blockIdx.y * 32;
  const int t = threadIdx.x;
  const int d = t & 63, rg = t >> 6;
  float ze = 0.f;
#pragma unroll
  for (int i = 0; i < 8; ++i) {
    float a = attn[((size_t)b*SS + q0 + 4*i + rg)*DD + d];
    ze += __expf(a);
  }
  __shared__ float red[4][64];
  red[rg][d] = ze;
  __syncthreads();
  if (t < 64)
    atomicAdd(&z2[b*DD + t], red[0][t] + red[1][t] + red[2][t] + red[3][t]);
}

// ---------------- K6: attn_w = exp(attn) / z2
__global__ __launch_bounds__(256) void k6w(
    const float* __restrict__ attn, const float* __restrict__ z2,
    float* __restrict__ out1)
{
  const size_t i = (size_t)blockIdx.x * 256 + threadIdx.x;
  const int b = (int)(i >> 18);        // SS*DD = 262144
  const int d = (int)(i & 63);
  out1[i] = __expf(attn[i]) / z2[b*DD + d];
}

extern "C" void kernel_launch(void* const* d_in, const int* in_sizes, int n_in,
                              void* d_out, int out_size, void* d_ws, size_t ws_size,
                              hipStream_t stream) {
  const float* q = (const float*)d_in[0];
  const float* k = (const float*)d_in[1];
  const float* v = (const float*)d_in[2];
  float* out0 = (float*)d_out;
  float* out1 = out0 + (size_t)BB * SS * DD;

  // bf16 Q/K scratch lives in the out1 region (overwritten by k6w at the end).
  ushort_t* QB = (ushort_t*)out1;                 // 2 MB
  ushort_t* KB = QB + (size_t)BB * SS * DD;       // 2 MB

  float* ws = (float*)d_ws;
  ushort_t* VT = (ushort_t*)ws;                              // 2 MB bf16
  float* Zp = (float*)(VT + (size_t)BB * DD * SS);           // QSPLIT*BB*SS
  float* z2 = Zp + (size_t)QSPLIT * BB * SS;                 // BB*DD

  hipLaunchKernelGGL(p0_convert, dim3(BB*SS*DD/4/256), dim3(256), 0, stream, q, k, QB, KB, out0, z2);
  hipLaunchKernelGGL(pa_colsum, dim3(SS/128, QSPLIT, BB), dim3(256), 0, stream, QB, KB, Zp);
  hipLaunchKernelGGL(p2_vt, dim3(SS/64, BB), dim3(256), 0, stream, v, Zp, VT);
  hipLaunchKernelGGL(pb_attn, dim3(SS/64, KSPLIT, BB), dim3(256), 0, stream, QB, KB, VT, out0);
  hipLaunchKernelGGL(k4f, dim3(BB, SS/32), dim3(256), 0, stream, out0, z2);
  hipLaunchKernelGGL(k6w, dim3(BB*SS*DD/256), dim3(256), 0, stream, out0, z2, out1);
}